// Round 10
// baseline (79.369 us; speedup 1.0000x reference)
//
#include <hip/hip_runtime.h>
#include <hip/hip_bf16.h>

// Problem constants (fixed by setup_inputs)
#define B_ROWS 16384
#define DDIM   1024
#define CCLS   1000
#define CPAD   1024   // classes padded to 1024 (pad rows zeroed -> acc 0 -> masked)
#define GN     4      // grid-N slices (CPAD / 256)
#define NKT    16     // K-tiles (1024 / 64)

typedef __attribute__((ext_vector_type(8))) short  short8;  // 8 bf16 (4 VGPRs)
typedef __attribute__((ext_vector_type(4))) float  f32x4;   // MFMA accumulator

#define FENCE asm volatile("" ::: "memory")   // compiler fence, no HW wait

// fp32 -> bf16 round-to-nearest-even
static __device__ __forceinline__ unsigned short f2bf(float f) {
    unsigned int u = __float_as_uint(f);
    unsigned int r = 0x7fffu + ((u >> 16) & 1u);
    return (unsigned short)((u + r) >> 16);
}
static __device__ __forceinline__ unsigned int pack2(float a, float b) {
    return (unsigned int)f2bf(a) | ((unsigned int)f2bf(b) << 16);
}

// async global->LDS DMA, 16 B/lane; lds dest is WAVE-UNIFORM base (HW adds lane*16)
static __device__ __forceinline__ void gl_lds16(const unsigned short* g, unsigned short* l) {
    __builtin_amdgcn_global_load_lds(
        (const __attribute__((address_space(1))) void*)g,
        (__attribute__((address_space(3))) void*)l, 16, 0, 0);
}

// ---------------------------------------------------------------------------
// Kernel 1: P fp32 -> Pb bf16 [1024,1024], pad rows zeroed. ~6 MB traffic.
// ---------------------------------------------------------------------------
__global__ __launch_bounds__(256) void prep_P(
        const float* __restrict__ P, unsigned short* __restrict__ Pb) {
    const int pb = blockIdx.x;   // 0..31 -> rows [pb*32, +32)
    #pragma unroll 4
    for (int c = 0; c < 32; ++c) {
        const int base = (pb * 8192 + c * 256 + threadIdx.x) * 4;
        const int row  = base >> 10;
        ushort4 o;
        if (row < CCLS) {
            const float4 q = *reinterpret_cast<const float4*>(P + base);
            o.x = f2bf(q.x); o.y = f2bf(q.y); o.z = f2bf(q.z); o.w = f2bf(q.w);
        } else {
            o.x = o.y = o.z = o.w = 0;
        }
        *reinterpret_cast<ushort4*>(Pb + base) = o;
    }
}

// ---------------------------------------------------------------------------
// Kernel 2: FUSED convert+normalize+GEMM+softmax-CE.
//   Reads H fp32 directly: reg-stage -> bf16 cvt -> swizzled ds_write, with
//   per-row ssq accumulated on the fly (norms only needed in the epilogue).
//   B staged from Pb via global_load_lds (inverse-swizzled source).
//   2-phase double-buffer, counted vmcnt(8), raw s_barrier (no vmcnt(0) drain).
//   grid = 256 blocks (1/CU), 512 threads = 8 waves (2M x 4N), 256x256 tile.
//   XCD-grouped grid map: the 4 bn-partners of each bm land on ONE XCD so the
//   4x re-read of H fp32 hits that XCD's L2.
// ---------------------------------------------------------------------------
__global__ __launch_bounds__(512, 2) void gemm_ce(
        const float* __restrict__ H,
        const unsigned short* __restrict__ Pb,
        const int* __restrict__ labels,
        float* __restrict__ psum,
        float* __restrict__ plab) {
    __shared__ unsigned short Alds[2][256 * 64];   // 32 KiB per buf
    __shared__ unsigned short Blds[2][256 * 64];   // total 128 KiB
    __shared__ float rowscale_lds[256];

    // bm = (xcd)*8 + hi, bn from bits 3-4: partners of a bm are origs 8 apart
    // (same XCD under round-robin dispatch), launched nearly together.
    const int orig = blockIdx.x;
    const int bm   = (orig & 7) * 8 + (orig >> 5);   // 0..63
    const int bn   = (orig >> 3) & 3;                // 0..3

    const int tid = threadIdx.x;
    const int w   = tid >> 6;    // wave 0..7
    const int l   = tid & 63;
    const int lo  = l & 15;
    const int hi  = l >> 4;
    const int wm  = w >> 2;      // 0..1
    const int wn  = w & 3;       // 0..3

    const size_t arow0 = (size_t)bm * 256;
    const size_t brow0 = (size_t)bn * 256;

    // Staging geometry: quarter q = 64 rows; wave w covers rows [q*64+w*8,+8),
    // lane l -> row +(l>>3), 16B chunk (l&7). LDS layout (both A and B):
    // LDS[r][c'] = G[r][c' ^ (r&7)] on the 16B granule.
    const int srow = l >> 3;
    const int lc   = l & 7;
    const int scol = (lc ^ srow) * 8;   // bf16 elems (B source inverse-swizzle)

    // B: gl_lds writes linearly; source col pre-swizzled.
#define B_STAGE(buf_, t_) do { _Pragma("unroll")                                \
    for (int q_ = 0; q_ < 4; ++q_)                                              \
        gl_lds16(Pb + (brow0 + q_ * 64 + w * 8 + srow) * DDIM + (t_) * 64 + scol,\
                 &Blds[buf_][(q_ * 64 + w * 8) * 64]);                          \
} while (0)

    // A: fp32 global -> va regs (issued one tile early; 8 dwordx4)
    float4 va[8];
#define A_LOAD(t_) do { _Pragma("unroll")                                       \
    for (int q_ = 0; q_ < 4; ++q_) {                                            \
        const float* s_ = H + (arow0 + q_ * 64 + w * 8 + srow) * DDIM           \
                            + (t_) * 64 + lc * 8;                               \
        va[q_ * 2]     = *reinterpret_cast<const float4*>(s_);                  \
        va[q_ * 2 + 1] = *reinterpret_cast<const float4*>(s_ + 4);              \
    } } while (0)

    // A: cvt + ssq + swizzled ds_write_b128 (linear source col lc, dest lc^srow)
    float ss[4] = {0.f, 0.f, 0.f, 0.f};
#define A_WRITE(buf_) do { _Pragma("unroll")                                    \
    for (int q_ = 0; q_ < 4; ++q_) {                                            \
        const float4 v0_ = va[q_ * 2], v1_ = va[q_ * 2 + 1];                    \
        ss[q_] += v0_.x*v0_.x + v0_.y*v0_.y + v0_.z*v0_.z + v0_.w*v0_.w         \
                + v1_.x*v1_.x + v1_.y*v1_.y + v1_.z*v1_.z + v1_.w*v1_.w;        \
        uint4 d_;                                                               \
        d_.x = pack2(v0_.x, v0_.y); d_.y = pack2(v0_.z, v0_.w);                 \
        d_.z = pack2(v1_.x, v1_.y); d_.w = pack2(v1_.z, v1_.w);                 \
        *reinterpret_cast<uint4*>((char*)&Alds[buf_][0]                         \
            + (q_ * 64 + w * 8 + srow) * 128 + (lc ^ srow) * 16) = d_;          \
    } } while (0)

    f32x4 acc[8][4];
    #pragma unroll
    for (int m = 0; m < 8; ++m)
        #pragma unroll
        for (int n = 0; n < 4; ++n)
            acc[m][n] = (f32x4){0.f, 0.f, 0.f, 0.f};

    const int swz = (lo & 7) << 4;   // read-side XOR (bytes)
    const int colk[2] = { (hi << 4) ^ swz, (64 | (hi << 4)) ^ swz };

#define COMPUTE(cur_) do {                                                      \
    const char* Ab_ = (const char*)&Alds[cur_][0];                              \
    const char* Bb_ = (const char*)&Blds[cur_][0];                              \
    _Pragma("unroll")                                                           \
    for (int kk_ = 0; kk_ < 2; ++kk_) {                                         \
        short8 a_[8], b_[4];                                                    \
        _Pragma("unroll")                                                       \
        for (int mi_ = 0; mi_ < 8; ++mi_)                                       \
            a_[mi_] = *reinterpret_cast<const short8*>(                         \
                Ab_ + (wm * 128 + mi_ * 16 + lo) * 128 + colk[kk_]);            \
        _Pragma("unroll")                                                       \
        for (int ni_ = 0; ni_ < 4; ++ni_)                                       \
            b_[ni_] = *reinterpret_cast<const short8*>(                         \
                Bb_ + (wn * 64 + ni_ * 16 + lo) * 128 + colk[kk_]);             \
        __builtin_amdgcn_s_setprio(1);                                          \
        _Pragma("unroll")                                                       \
        for (int ni_ = 0; ni_ < 4; ++ni_)                                       \
            _Pragma("unroll")                                                   \
            for (int mi_ = 0; mi_ < 8; ++mi_)                                   \
                acc[mi_][ni_] = __builtin_amdgcn_mfma_f32_16x16x32_bf16(        \
                    a_[mi_], b_[ni_], acc[mi_][ni_], 0, 0, 0);                  \
        __builtin_amdgcn_s_setprio(0);                                          \
    } } while (0)

    // Prologue: tile0 staged (A via regs, B via gl_lds), tile1 A-loads in flight
    A_LOAD(0);
    A_WRITE(0);                 // compiler auto-waits the va loads
    B_STAGE(0, 0);              // 4 gl_lds outstanding
    A_LOAD(1);                  // +8 -> 12 outstanding
    asm volatile("s_waitcnt vmcnt(8) lgkmcnt(0)" ::: "memory");  // drain B(t0)+ds_writes
    FENCE; __builtin_amdgcn_s_barrier(); FENCE;

    #pragma unroll 1
    for (int t = 0; t < NKT; ++t) {
        const int cur = t & 1;
        if (t + 1 < NKT) {
            B_STAGE(cur ^ 1, t + 1);    // regions freed by entry barrier
            A_WRITE(cur ^ 1);           // va = tile t+1 (loaded last iter);
                                        // auto-wait drains to <=4 (leaves B)
            if (t + 2 < NKT) A_LOAD(t + 2);   // refill va, +8 in flight
        }
        COMPUTE(cur);
        if (t + 2 < NKT) {
            // outstanding: B(t+1)=4 oldest + A(t+2)=8 -> drain B only
            asm volatile("s_waitcnt vmcnt(8) lgkmcnt(0)" ::: "memory");
        } else if (t + 1 < NKT) {
            asm volatile("s_waitcnt vmcnt(0) lgkmcnt(0)" ::: "memory");
        }
        if (t + 1 < NKT) { FENCE; __builtin_amdgcn_s_barrier(); FENCE; }
    }
#undef COMPUTE
#undef A_WRITE
#undef A_LOAD
#undef B_STAGE

    // ---- Row norms: reduce ss over the 8 lanes sharing (w, srow) ----
    #pragma unroll
    for (int q = 0; q < 4; ++q) {
        ss[q] += __shfl_xor(ss[q], 1);
        ss[q] += __shfl_xor(ss[q], 2);
        ss[q] += __shfl_xor(ss[q], 4);
    }
    if (lc == 0) {
        #pragma unroll
        for (int q = 0; q < 4; ++q)
            rowscale_lds[q * 64 + w * 8 + srow] =
                1.4426950408889634f * rsqrtf(ss[q]);   // log2(e)/||h||, tau=1
    }
    asm volatile("s_waitcnt lgkmcnt(0)" ::: "memory");
    FENCE; __builtin_amdgcn_s_barrier(); FENCE;

    // ---- Fused epilogue: logits -> exp2 partial sums + label logit capture.
    //      C/D: class c = bn*256 + wn*64 + n*16 + lo ; row = wm*128 + m*16 + hi*4 + j
    //      red reuses Alds[0]; last compute tile was buf 1 (NKT even) -> safe.
    float* red = reinterpret_cast<float*>(&Alds[0][0]);   // [256 rows][4 wn][2]
    #pragma unroll
    for (int m = 0; m < 8; ++m) {
        const int rloc = wm * 128 + m * 16 + hi * 4;
        float rs4[4], s4[4], lb2[4];
        int   lb4[4];
        #pragma unroll
        for (int j = 0; j < 4; ++j) {
            rs4[j] = rowscale_lds[rloc + j];
            lb4[j] = labels[arow0 + rloc + j];
            s4[j]  = 0.f;
            lb2[j] = -1e30f;
        }
        #pragma unroll
        for (int n = 0; n < 4; ++n) {
            const int c = (int)brow0 + wn * 64 + n * 16 + lo;
            const float pen = (c < CCLS) ? 0.f : -1e30f;
            #pragma unroll
            for (int j = 0; j < 4; ++j) {
                const float lg = fmaf(acc[m][n][j], rs4[j], pen);
                lb2[j] = (c == lb4[j]) ? lg : lb2[j];
                s4[j] += exp2f(lg);
            }
        }
        #pragma unroll
        for (int j = 0; j < 4; ++j) {
            #pragma unroll
            for (int mask = 1; mask <= 8; mask <<= 1) {
                s4[j]  += __shfl_xor(s4[j], mask);
                lb2[j]  = fmaxf(lb2[j], __shfl_xor(lb2[j], mask));
            }
            if (lo == 0) {
                const int r = rloc + j;
                red[(r * 4 + wn) * 2 + 0] = s4[j];
                red[(r * 4 + wn) * 2 + 1] = lb2[j];
            }
        }
    }
    __syncthreads();
    if (tid < 256) {
        float st = 0.f, lt = -1e30f;
        #pragma unroll
        for (int q = 0; q < 4; ++q) {
            st += red[(tid * 4 + q) * 2 + 0];
            lt  = fmaxf(lt, red[(tid * 4 + q) * 2 + 1]);
        }
        const size_t grow = arow0 + tid;
        psum[grow * GN + bn] = st;
        plab[grow * GN + bn] = lt;
    }
}

// ---------------------------------------------------------------------------
// Kernel 3: per-row loss, 64 blocks x 256 rows -> 64 partials (grid-parallel)
// ---------------------------------------------------------------------------
__global__ __launch_bounds__(256) void reduce1(
        const float* __restrict__ psum, const float* __restrict__ plab,
        float* __restrict__ partials) {
    const int tid = threadIdx.x;
    const size_t row = (size_t)blockIdx.x * 256 + tid;
    const float4 ps = *reinterpret_cast<const float4*>(psum + row * GN);
    const float4 pl = *reinterpret_cast<const float4*>(plab + row * GN);
    const float st = (ps.x + ps.y) + (ps.z + ps.w);
    const float lt = fmaxf(fmaxf(pl.x, pl.y), fmaxf(pl.z, pl.w));
    float loss = 0.6931471805599453f * (log2f(st) - lt);
    #pragma unroll
    for (int mask = 1; mask < 64; mask <<= 1)
        loss += __shfl_xor(loss, mask);
    __shared__ float wsum[4];
    if ((tid & 63) == 0) wsum[tid >> 6] = loss;
    __syncthreads();
    if (tid == 0)
        partials[blockIdx.x] = wsum[0] + wsum[1] + wsum[2] + wsum[3];
}

// Kernel 4: final 64 -> 1 mean
__global__ void reduce2(const float* __restrict__ partials, float* __restrict__ out) {
    float v = partials[threadIdx.x];   // 64 threads
    #pragma unroll
    for (int mask = 1; mask < 64; mask <<= 1)
        v += __shfl_xor(v, mask);
    if (threadIdx.x == 0) out[0] = v * (1.0f / 16384.0f);
}

extern "C" void kernel_launch(void* const* d_in, const int* in_sizes, int n_in,
                              void* d_out, int out_size, void* d_ws, size_t ws_size,
                              hipStream_t stream) {
    const float* H      = (const float*)d_in[0];   // [16384, 1024] fp32
    const float* P      = (const float*)d_in[1];   // [1000, 1024] fp32
    const int*   labels = (const int*)d_in[2];     // [16384] int32
    float* out = (float*)d_out;

    // ws layout (~2.6 MiB): Pb 2M | psum 256K | plab 256K | partials 256B
    char* wp = (char*)d_ws;
    unsigned short* Pb = (unsigned short*)wp;   wp += (size_t)CPAD * DDIM * 2;
    float* psum        = (float*)wp;            wp += (size_t)B_ROWS * GN * 4;
    float* plab        = (float*)wp;            wp += (size_t)B_ROWS * GN * 4;
    float* partials    = (float*)wp;

    prep_P<<<32, 256, 0, stream>>>(P, Pb);
    gemm_ce<<<(B_ROWS / 256) * GN, 512, 0, stream>>>(H, Pb, labels, psum, plab);
    reduce1<<<B_ROWS / 256, 256, 0, stream>>>(psum, plab, partials);
    reduce2<<<1, 64, 0, stream>>>(partials, out);
}

// Round 11
// 71.841 us; speedup vs baseline: 1.1048x; 1.1048x over previous
//
#include <hip/hip_runtime.h>
#include <hip/hip_bf16.h>

// Problem constants (fixed by setup_inputs)
#define B_ROWS 16384
#define DDIM   1024
#define CCLS   1000
#define CPAD   1024   // classes padded to 1024 (pad rows zeroed -> acc 0 -> masked)
#define GN     4      // grid-N slices (CPAD / 256)
#define NKT    16     // K-tiles (1024 / 64)

typedef __attribute__((ext_vector_type(8))) short  short8;  // 8 bf16 (4 VGPRs)
typedef __attribute__((ext_vector_type(4))) float  f32x4;   // MFMA accumulator

// fp32 -> bf16 round-to-nearest-even
static __device__ __forceinline__ unsigned short f2bf(float f) {
    unsigned int u = __float_as_uint(f);
    unsigned int r = 0x7fffu + ((u >> 16) & 1u);
    return (unsigned short)((u + r) >> 16);
}

// async global->LDS DMA, 16 B/lane; lds dest is WAVE-UNIFORM base (HW adds lane*16)
static __device__ __forceinline__ void gl_lds16(const unsigned short* g, unsigned short* l) {
    __builtin_amdgcn_global_load_lds(
        (const __attribute__((address_space(1))) void*)g,
        (__attribute__((address_space(3))) void*)l, 16, 0, 0);
}

// ---------------------------------------------------------------------------
// Kernel 1: prep — H -> bf16 Hb + rowscale = log2(e)/||h||; P -> Pb (padded).
//   H blocks (0..1023): 16 rows each; each wave owns 4 rows CONCURRENTLY
//   (16 dwordx4 loads in flight per wave -> latency covered).
// ---------------------------------------------------------------------------
__global__ __launch_bounds__(256) void prep(
        const float* __restrict__ H, const float* __restrict__ P,
        unsigned short* __restrict__ Hb, unsigned short* __restrict__ Pb,
        float* __restrict__ rowscale) {
    const int bid = blockIdx.x;
    const int tid = threadIdx.x;
    const int w   = tid >> 6;
    const int l   = tid & 63;
    if (bid < 1024) {
        const int row0 = bid * 16 + w * 4;
        float4 v[4][4];
        #pragma unroll
        for (int r = 0; r < 4; ++r)
            #pragma unroll
            for (int c = 0; c < 4; ++c)
                v[r][c] = *reinterpret_cast<const float4*>(
                    H + (size_t)(row0 + r) * DDIM + c * 256 + l * 4);
        float ss[4];
        #pragma unroll
        for (int r = 0; r < 4; ++r) {
            unsigned short* dst = Hb + (size_t)(row0 + r) * DDIM;
            ss[r] = 0.f;
            #pragma unroll
            for (int c = 0; c < 4; ++c) {
                const float4 q = v[r][c];
                ss[r] += q.x*q.x + q.y*q.y + q.z*q.z + q.w*q.w;
                ushort4 o = {f2bf(q.x), f2bf(q.y), f2bf(q.z), f2bf(q.w)};
                *reinterpret_cast<ushort4*>(dst + c * 256 + l * 4) = o;
            }
        }
        #pragma unroll
        for (int mask = 1; mask < 64; mask <<= 1)
            #pragma unroll
            for (int r = 0; r < 4; ++r)       // 4 independent chains interleave
                ss[r] += __shfl_xor(ss[r], mask);
        if (l == 0) {
            #pragma unroll
            for (int r = 0; r < 4; ++r)
                rowscale[row0 + r] = 1.4426950408889634f * rsqrtf(ss[r]);
        }
    } else {
        const int pb = bid - 1024;   // 0..31 -> rows [pb*32, +32) of Pb
        #pragma unroll 4
        for (int c = 0; c < 32; ++c) {
            const int base = (pb * 8192 + c * 256 + tid) * 4;
            const int row  = base >> 10;
            ushort4 o;
            if (row < CCLS) {
                const float4 q = *reinterpret_cast<const float4*>(P + base);
                o.x = f2bf(q.x); o.y = f2bf(q.y); o.z = f2bf(q.z); o.w = f2bf(q.w);
            } else {
                o.x = o.y = o.z = o.w = 0;
            }
            *reinterpret_cast<ushort4*>(Pb + base) = o;
        }
    }
}

// ---------------------------------------------------------------------------
// Kernel 2: 256x256-tile GEMM, BK=64, 8-PHASE schedule (T2+T3+T4+T5) —
// the measured-best variant (round 6: 42.7 us, 805 TF). Per K-tile 4 phases
// of {ds-read subtile | stage 1 quarter | barrier | lgkmcnt(0) | 16 MFMA |
// barrier}; vmcnt(6) once per K-tile (never 0 in the loop body).
// XOR-swizzled LDS both-sides (linear gl_lds dest + inverse-swizzled source).
//   grid = 64(M) x 4(N) = 256 blocks (1/CU), 512 threads = 8 waves (2M x 4N);
//   wave (wm,wn) owns 128x64 output: acc[8][4]; all 8 B-frags kept live.
// ---------------------------------------------------------------------------
__global__ __launch_bounds__(512, 2) void gemm_ce(
        const unsigned short* __restrict__ Hb,
        const unsigned short* __restrict__ Pb,
        const int* __restrict__ labels,
        const float* __restrict__ rowscale,
        float* __restrict__ psum,
        float* __restrict__ plab) {
    __shared__ unsigned short Alds[2][256 * 64];   // 32 KiB per buf
    __shared__ unsigned short Blds[2][256 * 64];   // total 128 KiB

    // Bijective XCD swizzle (nwg=256 % 8 == 0): XCD gets 8 contiguous bm,
    // each with all 4 bn (A-panel + Pb both L2-hot per XCD).
    const int orig = blockIdx.x;
    const int wg   = (orig & 7) * 32 + (orig >> 3);
    const int bm   = wg >> 2;    // 0..63
    const int bn   = wg & 3;     // 0..3

    const int tid = threadIdx.x;
    const int w   = tid >> 6;    // wave 0..7
    const int l   = tid & 63;
    const int lo  = l & 15;
    const int hi  = l >> 4;
    const int wm  = w >> 2;      // 0..1
    const int wn  = w & 3;       // 0..3

    const size_t arow0 = (size_t)bm * 256;
    const size_t brow0 = (size_t)bn * 256;

    // Staging geometry: one quarter (64 rows x 64 cols bf16 = 8 KiB) per issue;
    // wave w covers rows [q*64 + w*8, +8), lane l -> row +(l>>3), 16B chunk (l&7).
    // LDS dest linear; SOURCE col inverse-swizzled: LDS[r][c'] = G[r][c'^(r&7)].
    const int srow = l >> 3;
    const int scol = ((l & 7) ^ srow) * 8;   // bf16 elems

#define STAGE_A(buf_, t_, q_) gl_lds16(                                         \
        Hb + (arow0 + (q_) * 64 + w * 8 + srow) * DDIM + (t_) * 64 + scol,      \
        &Alds[buf_][((q_) * 64 + w * 8) * 64])
#define STAGE_B(buf_, t_, q_) gl_lds16(                                         \
        Pb + (brow0 + (q_) * 64 + w * 8 + srow) * DDIM + (t_) * 64 + scol,      \
        &Blds[buf_][((q_) * 64 + w * 8) * 64])

    f32x4 acc[8][4];
    #pragma unroll
    for (int m = 0; m < 8; ++m)
        #pragma unroll
        for (int n = 0; n < 4; ++n)
            acc[m][n] = (f32x4){0.f, 0.f, 0.f, 0.f};

    const int swz   = (lo & 7) << 4;          // read-side XOR (bytes)
    const int colk0 = (hi << 4) ^ swz;        // kk=0 byte col
    const int colk1 = (64 | (hi << 4)) ^ swz; // kk=1 byte col

    short8 a[4][2];   // current m-half A frags
    short8 b[4][2];   // ALL n B frags (kept live across phases)

#define LDA(base_, mh_) do { _Pragma("unroll")                                  \
    for (int mi_ = 0; mi_ < 4; ++mi_) {                                         \
        const int r_ = (wm * 128 + (mh_) * 64 + mi_ * 16 + lo) * 128;           \
        a[mi_][0] = *reinterpret_cast<const short8*>((base_) + r_ + colk0);     \
        a[mi_][1] = *reinterpret_cast<const short8*>((base_) + r_ + colk1);     \
    } } while (0)
#define LDB(base_, nh_) do { _Pragma("unroll")                                  \
    for (int ni_ = 0; ni_ < 2; ++ni_) {                                         \
        const int r_ = (wn * 64 + ((nh_) * 2 + ni_) * 16 + lo) * 128;           \
        b[(nh_)*2+ni_][0] = *reinterpret_cast<const short8*>((base_) + r_ + colk0); \
        b[(nh_)*2+ni_][1] = *reinterpret_cast<const short8*>((base_) + r_ + colk1); \
    } } while (0)
#define MFMA_Q(mh_, nh_) do { _Pragma("unroll")                                 \
    for (int kk_ = 0; kk_ < 2; ++kk_) { _Pragma("unroll")                       \
    for (int ni_ = 0; ni_ < 2; ++ni_) { _Pragma("unroll")                       \
    for (int mi_ = 0; mi_ < 4; ++mi_) {                                         \
        acc[(mh_)*4+mi_][(nh_)*2+ni_] = __builtin_amdgcn_mfma_f32_16x16x32_bf16(\
            a[mi_][kk_], b[(nh_)*2+ni_][kk_], acc[(mh_)*4+mi_][(nh_)*2+ni_],    \
            0, 0, 0);                                                           \
    } } } } while (0)
#define PHASE_TAIL(mh_, nh_)                                                    \
    __builtin_amdgcn_s_barrier();                                               \
    asm volatile("s_waitcnt lgkmcnt(0)" ::: "memory");                          \
    __builtin_amdgcn_sched_barrier(0);                                          \
    __builtin_amdgcn_s_setprio(1);                                              \
    MFMA_Q(mh_, nh_);                                                           \
    __builtin_amdgcn_s_setprio(0);                                              \
    __builtin_amdgcn_s_barrier()

// One K-tile = 4 phases. Stage-hazard ledger (region -> last reader -> stage):
//  Aq0/Aq2 of buf p: read ph0 -> staged (t+2) at ph1
//  Bq0..3  of buf p: read ph0-ph1 -> staged (t+2) at ph2/ph3
//  Aq1/Aq3 of buf p: read ph2 -> staged (t+2) at next iteration's ph0
// vmcnt(6) at ph3 = 3 quarters (ph1+ph2+ph3 issues) in flight; guarantees
// tile t+1 (incl. its Aq1/Aq3 staged at THIS iteration's ph0) complete.
#define TILE_ITER(p_, t_) do {                                                  \
    const char* Ab_ = (const char*)&Alds[p_][0];                                \
    const char* Bb_ = (const char*)&Blds[p_][0];                                \
    /* phase 0 */                                                               \
    LDA(Ab_, 0); LDB(Bb_, 0);                                                   \
    if ((t_) + 1 < NKT) { STAGE_A((p_) ^ 1, (t_) + 1, 1);                       \
                          STAGE_A((p_) ^ 1, (t_) + 1, 3); }                     \
    PHASE_TAIL(0, 0);                                                           \
    /* phase 1 */                                                               \
    LDB(Bb_, 1);                                                                \
    if ((t_) + 2 < NKT) { STAGE_A(p_, (t_) + 2, 0); STAGE_A(p_, (t_) + 2, 2); } \
    PHASE_TAIL(0, 1);                                                           \
    /* phase 2 */                                                               \
    LDA(Ab_, 1);                                                                \
    if ((t_) + 2 < NKT) { STAGE_B(p_, (t_) + 2, 0); STAGE_B(p_, (t_) + 2, 1); } \
    PHASE_TAIL(1, 0);                                                           \
    /* phase 3 */                                                               \
    if ((t_) + 2 < NKT) { STAGE_B(p_, (t_) + 2, 2); STAGE_B(p_, (t_) + 2, 3);   \
        asm volatile("s_waitcnt vmcnt(6)" ::: "memory");                        \
    } else if ((t_) + 1 < NKT) {                                                \
        asm volatile("s_waitcnt vmcnt(0)" ::: "memory");                        \
    }                                                                           \
    PHASE_TAIL(1, 1);                                                           \
} while (0)

    // Prologue: tile0 fully + tile1 {Aq0,Aq2,Bq0..3} (its Aq1,Aq3 land at iter0 ph0)
    #pragma unroll
    for (int q = 0; q < 4; ++q) { STAGE_A(0, 0, q); STAGE_B(0, 0, q); }
    STAGE_A(1, 1, 0); STAGE_A(1, 1, 2);
    #pragma unroll
    for (int q = 0; q < 4; ++q) STAGE_B(1, 1, q);
    asm volatile("s_waitcnt vmcnt(6)" ::: "memory");   // tile0 complete
    __builtin_amdgcn_s_barrier();

    #pragma unroll 1
    for (int kt2 = 0; kt2 < NKT / 2; ++kt2) {
        const int t0 = 2 * kt2;
        TILE_ITER(0, t0);
        TILE_ITER(1, t0 + 1);
    }
#undef TILE_ITER
#undef PHASE_TAIL
#undef MFMA_Q
#undef LDB
#undef LDA
#undef STAGE_B
#undef STAGE_A

    // ---- Fused epilogue (per-m to bound VGPR): logits -> exp2 sums + label.
    //      C/D: class c = bn*256 + wn*64 + n*16 + lo ; row = wm*128 + m*16 + hi*4 + j
    float* red = reinterpret_cast<float*>(&Alds[0][0]);   // [256 rows][4 wn][2]
    #pragma unroll
    for (int m = 0; m < 8; ++m) {
        const int rloc = wm * 128 + m * 16 + hi * 4;
        float rs4[4], s4[4], lb2[4];
        int   lb4[4];
        #pragma unroll
        for (int j = 0; j < 4; ++j) {
            const size_t grow = arow0 + rloc + j;
            rs4[j] = rowscale[grow];   // log2(e)/||h||  (tau = 1)
            lb4[j] = labels[grow];
            s4[j]  = 0.f;
            lb2[j] = -1e30f;
        }
        #pragma unroll
        for (int n = 0; n < 4; ++n) {
            const int c = (int)brow0 + wn * 64 + n * 16 + lo;
            const float pen = (c < CCLS) ? 0.f : -1e30f;
            #pragma unroll
            for (int j = 0; j < 4; ++j) {
                const float lg = fmaf(acc[m][n][j], rs4[j], pen);
                lb2[j] = (c == lb4[j]) ? lg : lb2[j];
                s4[j] += exp2f(lg);
            }
        }
        #pragma unroll
        for (int j = 0; j < 4; ++j) {
            #pragma unroll
            for (int mask = 1; mask <= 8; mask <<= 1) {
                s4[j]  += __shfl_xor(s4[j], mask);
                lb2[j]  = fmaxf(lb2[j], __shfl_xor(lb2[j], mask));
            }
            if (lo == 0) {
                const int r = rloc + j;
                red[(r * 4 + wn) * 2 + 0] = s4[j];
                red[(r * 4 + wn) * 2 + 1] = lb2[j];
            }
        }
    }
    __syncthreads();
    if (tid < 256) {
        float st = 0.f, lt = -1e30f;
        #pragma unroll
        for (int q = 0; q < 4; ++q) {
            st += red[(tid * 4 + q) * 2 + 0];
            lt  = fmaxf(lt, red[(tid * 4 + q) * 2 + 1]);
        }
        const size_t grow = arow0 + tid;
        psum[grow * GN + bn] = st;
        plab[grow * GN + bn] = lt;
    }
}

// ---------------------------------------------------------------------------
// Kernel 3: per-row loss, 64 blocks x 256 rows -> 64 partials (grid-parallel)
// ---------------------------------------------------------------------------
__global__ __launch_bounds__(256) void reduce1(
        const float* __restrict__ psum, const float* __restrict__ plab,
        float* __restrict__ partials) {
    const int tid = threadIdx.x;
    const size_t row = (size_t)blockIdx.x * 256 + tid;
    const float4 ps = *reinterpret_cast<const float4*>(psum + row * GN);
    const float4 pl = *reinterpret_cast<const float4*>(plab + row * GN);
    const float st = (ps.x + ps.y) + (ps.z + ps.w);
    const float lt = fmaxf(fmaxf(pl.x, pl.y), fmaxf(pl.z, pl.w));
    float loss = 0.6931471805599453f * (log2f(st) - lt);
    #pragma unroll
    for (int mask = 1; mask < 64; mask <<= 1)
        loss += __shfl_xor(loss, mask);
    __shared__ float wsum[4];
    if ((tid & 63) == 0) wsum[tid >> 6] = loss;
    __syncthreads();
    if (tid == 0)
        partials[blockIdx.x] = wsum[0] + wsum[1] + wsum[2] + wsum[3];
}

// Kernel 4: final 64 -> 1 mean
__global__ void reduce2(const float* __restrict__ partials, float* __restrict__ out) {
    float v = partials[threadIdx.x];   // 64 threads
    #pragma unroll
    for (int mask = 1; mask < 64; mask <<= 1)
        v += __shfl_xor(v, mask);
    if (threadIdx.x == 0) out[0] = v * (1.0f / 16384.0f);
}

extern "C" void kernel_launch(void* const* d_in, const int* in_sizes, int n_in,
                              void* d_out, int out_size, void* d_ws, size_t ws_size,
                              hipStream_t stream) {
    const float* H      = (const float*)d_in[0];   // [16384, 1024] fp32
    const float* P      = (const float*)d_in[1];   // [1000, 1024] fp32
    const int*   labels = (const int*)d_in[2];     // [16384] int32
    float* out = (float*)d_out;

    // ws layout (~34.6 MiB): Hb 32M | Pb 2M | rowscale 64K | psum 256K | plab 256K
    char* wp = (char*)d_ws;
    unsigned short* Hb = (unsigned short*)wp;   wp += (size_t)B_ROWS * DDIM * 2;
    unsigned short* Pb = (unsigned short*)wp;   wp += (size_t)CPAD * DDIM * 2;
    float* rowscale    = (float*)wp;            wp += (size_t)B_ROWS * 4;
    float* psum        = (float*)wp;            wp += (size_t)B_ROWS * GN * 4;
    float* plab        = (float*)wp;            wp += (size_t)B_ROWS * GN * 4;
    float* partials    = (float*)wp;

    prep<<<1056, 256, 0, stream>>>(H, P, Hb, Pb, rowscale);
    gemm_ce<<<(B_ROWS / 256) * GN, 512, 0, stream>>>(Hb, Pb, labels, rowscale, psum, plab);
    reduce1<<<B_ROWS / 256, 256, 0, stream>>>(psum, plab, partials);
    reduce2<<<1, 64, 0, stream>>>(partials, out);
}

// Round 12
// 70.920 us; speedup vs baseline: 1.1191x; 1.0130x over previous
//
#include <hip/hip_runtime.h>
#include <hip/hip_bf16.h>

// Problem constants (fixed by setup_inputs)
#define B_ROWS 16384
#define DDIM   1024
#define CCLS   1000
#define CPAD   1024   // classes padded to 1024 (pad rows zeroed -> acc 0 -> masked)
#define GN     4      // grid-N slices (CPAD / 256)
#define NKT    16     // K-tiles (1024 / 64)

typedef __attribute__((ext_vector_type(8))) short  short8;  // 8 bf16 (4 VGPRs)
typedef __attribute__((ext_vector_type(4))) float  f32x4;   // MFMA accumulator

// fp32 -> bf16 round-to-nearest-even
static __device__ __forceinline__ unsigned short f2bf(float f) {
    unsigned int u = __float_as_uint(f);
    unsigned int r = 0x7fffu + ((u >> 16) & 1u);
    return (unsigned short)((u + r) >> 16);
}

// async global->LDS DMA, 16 B/lane; lds dest is WAVE-UNIFORM base (HW adds lane*16)
static __device__ __forceinline__ void gl_lds16(const unsigned short* g, unsigned short* l) {
    __builtin_amdgcn_global_load_lds(
        (const __attribute__((address_space(1))) void*)g,
        (__attribute__((address_space(3))) void*)l, 16, 0, 0);
}

// ---------------------------------------------------------------------------
// Kernel 1: prep — H -> bf16 Hb + rowscale = log2(e)/||h||; P -> Pb (padded).
//   H blocks (0..2047): 8 rows each, 2 rows per wave. The 8 dwordx4 loads are
//   issued as one batch and PINNED ahead of the convert phase by
//   sched_barrier(0) (round-10 post-mortem: without it the compiler serialized
//   into load->use chunks -> VGPR_Count 32, ~4 loads in flight, 1.6 TB/s).
//   8 blocks/CU resident (VGPR ~64, no LDS) -> 32 waves/CU TLP.
// ---------------------------------------------------------------------------
__global__ __launch_bounds__(256) void prep(
        const float* __restrict__ H, const float* __restrict__ P,
        unsigned short* __restrict__ Hb, unsigned short* __restrict__ Pb,
        float* __restrict__ rowscale) {
    const int bid = blockIdx.x;
    const int tid = threadIdx.x;
    const int w   = tid >> 6;
    const int l   = tid & 63;
    if (bid < 2048) {
        const int row0 = bid * 8 + w * 2;
        float4 v[2][4];
        #pragma unroll
        for (int r = 0; r < 2; ++r)
            #pragma unroll
            for (int c = 0; c < 4; ++c)
                v[r][c] = *reinterpret_cast<const float4*>(
                    H + (size_t)(row0 + r) * DDIM + c * 256 + l * 4);
        __builtin_amdgcn_sched_barrier(0);   // keep all 8 loads in flight
        float ss[2];
        #pragma unroll
        for (int r = 0; r < 2; ++r) {
            unsigned short* dst = Hb + (size_t)(row0 + r) * DDIM;
            ss[r] = 0.f;
            #pragma unroll
            for (int c = 0; c < 4; ++c) {
                const float4 q = v[r][c];
                ss[r] += q.x*q.x + q.y*q.y + q.z*q.z + q.w*q.w;
                ushort4 o = {f2bf(q.x), f2bf(q.y), f2bf(q.z), f2bf(q.w)};
                *reinterpret_cast<ushort4*>(dst + c * 256 + l * 4) = o;
            }
        }
        #pragma unroll
        for (int mask = 1; mask < 64; mask <<= 1)
            #pragma unroll
            for (int r = 0; r < 2; ++r)       // 2 independent chains interleave
                ss[r] += __shfl_xor(ss[r], mask);
        if (l == 0) {
            #pragma unroll
            for (int r = 0; r < 2; ++r)
                rowscale[row0 + r] = 1.4426950408889634f * rsqrtf(ss[r]);
        }
    } else {
        const int pb = bid - 2048;   // 0..31 -> rows [pb*32, +32) of Pb
        #pragma unroll 4
        for (int c = 0; c < 32; ++c) {
            const int base = (pb * 8192 + c * 256 + tid) * 4;
            const int row  = base >> 10;
            ushort4 o;
            if (row < CCLS) {
                const float4 q = *reinterpret_cast<const float4*>(P + base);
                o.x = f2bf(q.x); o.y = f2bf(q.y); o.z = f2bf(q.z); o.w = f2bf(q.w);
            } else {
                o.x = o.y = o.z = o.w = 0;
            }
            *reinterpret_cast<ushort4*>(Pb + base) = o;
        }
    }
}

// ---------------------------------------------------------------------------
// Kernel 2: 256x256-tile GEMM, BK=64, 8-PHASE schedule (T2+T3+T4+T5) —
// measured-best variant (42.7 us, ~805 TF; verbatim from round 6/10).
// Per K-tile 4 phases of {ds-read subtile | stage 1 quarter | barrier |
// lgkmcnt(0) | 16 MFMA | barrier}; vmcnt(6) once per K-tile.
// XOR-swizzled LDS both-sides (linear gl_lds dest + inverse-swizzled source).
//   grid = 64(M) x 4(N) = 256 blocks (1/CU), 512 threads = 8 waves (2M x 4N);
//   wave (wm,wn) owns 128x64 output: acc[8][4]; all 8 B-frags kept live.
// ---------------------------------------------------------------------------
__global__ __launch_bounds__(512, 2) void gemm_ce(
        const unsigned short* __restrict__ Hb,
        const unsigned short* __restrict__ Pb,
        const int* __restrict__ labels,
        const float* __restrict__ rowscale,
        float* __restrict__ psum,
        float* __restrict__ plab) {
    __shared__ unsigned short Alds[2][256 * 64];   // 32 KiB per buf
    __shared__ unsigned short Blds[2][256 * 64];   // total 128 KiB

    // Bijective XCD swizzle (nwg=256 % 8 == 0): XCD gets 8 contiguous bm,
    // each with all 4 bn (A-panel + Pb both L2-hot per XCD).
    const int orig = blockIdx.x;
    const int wg   = (orig & 7) * 32 + (orig >> 3);
    const int bm   = wg >> 2;    // 0..63
    const int bn   = wg & 3;     // 0..3

    const int tid = threadIdx.x;
    const int w   = tid >> 6;    // wave 0..7
    const int l   = tid & 63;
    const int lo  = l & 15;
    const int hi  = l >> 4;
    const int wm  = w >> 2;      // 0..1
    const int wn  = w & 3;       // 0..3

    const size_t arow0 = (size_t)bm * 256;
    const size_t brow0 = (size_t)bn * 256;

    // Staging geometry: one quarter (64 rows x 64 cols bf16 = 8 KiB) per issue;
    // wave w covers rows [q*64 + w*8, +8), lane l -> row +(l>>3), 16B chunk (l&7).
    // LDS dest linear; SOURCE col inverse-swizzled: LDS[r][c'] = G[r][c'^(r&7)].
    const int srow = l >> 3;
    const int scol = ((l & 7) ^ srow) * 8;   // bf16 elems

#define STAGE_A(buf_, t_, q_) gl_lds16(                                         \
        Hb + (arow0 + (q_) * 64 + w * 8 + srow) * DDIM + (t_) * 64 + scol,      \
        &Alds[buf_][((q_) * 64 + w * 8) * 64])
#define STAGE_B(buf_, t_, q_) gl_lds16(                                         \
        Pb + (brow0 + (q_) * 64 + w * 8 + srow) * DDIM + (t_) * 64 + scol,      \
        &Blds[buf_][((q_) * 64 + w * 8) * 64])

    f32x4 acc[8][4];
    #pragma unroll
    for (int m = 0; m < 8; ++m)
        #pragma unroll
        for (int n = 0; n < 4; ++n)
            acc[m][n] = (f32x4){0.f, 0.f, 0.f, 0.f};

    const int swz   = (lo & 7) << 4;          // read-side XOR (bytes)
    const int colk0 = (hi << 4) ^ swz;        // kk=0 byte col
    const int colk1 = (64 | (hi << 4)) ^ swz; // kk=1 byte col

    short8 a[4][2];   // current m-half A frags
    short8 b[4][2];   // ALL n B frags (kept live across phases)

#define LDA(base_, mh_) do { _Pragma("unroll")                                  \
    for (int mi_ = 0; mi_ < 4; ++mi_) {                                         \
        const int r_ = (wm * 128 + (mh_) * 64 + mi_ * 16 + lo) * 128;           \
        a[mi_][0] = *reinterpret_cast<const short8*>((base_) + r_ + colk0);     \
        a[mi_][1] = *reinterpret_cast<const short8*>((base_) + r_ + colk1);     \
    } } while (0)
#define LDB(base_, nh_) do { _Pragma("unroll")                                  \
    for (int ni_ = 0; ni_ < 2; ++ni_) {                                         \
        const int r_ = (wn * 64 + ((nh_) * 2 + ni_) * 16 + lo) * 128;           \
        b[(nh_)*2+ni_][0] = *reinterpret_cast<const short8*>((base_) + r_ + colk0); \
        b[(nh_)*2+ni_][1] = *reinterpret_cast<const short8*>((base_) + r_ + colk1); \
    } } while (0)
#define MFMA_Q(mh_, nh_) do { _Pragma("unroll")                                 \
    for (int kk_ = 0; kk_ < 2; ++kk_) { _Pragma("unroll")                       \
    for (int ni_ = 0; ni_ < 2; ++ni_) { _Pragma("unroll")                       \
    for (int mi_ = 0; mi_ < 4; ++mi_) {                                         \
        acc[(mh_)*4+mi_][(nh_)*2+ni_] = __builtin_amdgcn_mfma_f32_16x16x32_bf16(\
            a[mi_][kk_], b[(nh_)*2+ni_][kk_], acc[(mh_)*4+mi_][(nh_)*2+ni_],    \
            0, 0, 0);                                                           \
    } } } } while (0)
#define PHASE_TAIL(mh_, nh_)                                                    \
    __builtin_amdgcn_s_barrier();                                               \
    asm volatile("s_waitcnt lgkmcnt(0)" ::: "memory");                          \
    __builtin_amdgcn_sched_barrier(0);                                          \
    __builtin_amdgcn_s_setprio(1);                                              \
    MFMA_Q(mh_, nh_);                                                           \
    __builtin_amdgcn_s_setprio(0);                                              \
    __builtin_amdgcn_s_barrier()

// One K-tile = 4 phases. Stage-hazard ledger (region -> last reader -> stage):
//  Aq0/Aq2 of buf p: read ph0 -> staged (t+2) at ph1
//  Bq0..3  of buf p: read ph0-ph1 -> staged (t+2) at ph2/ph3
//  Aq1/Aq3 of buf p: read ph2 -> staged (t+2) at next iteration's ph0
// vmcnt(6) at ph3 = 3 quarters (ph1+ph2+ph3 issues) in flight; guarantees
// tile t+1 (incl. its Aq1/Aq3 staged at THIS iteration's ph0) complete.
#define TILE_ITER(p_, t_) do {                                                  \
    const char* Ab_ = (const char*)&Alds[p_][0];                                \
    const char* Bb_ = (const char*)&Blds[p_][0];                                \
    /* phase 0 */                                                               \
    LDA(Ab_, 0); LDB(Bb_, 0);                                                   \
    if ((t_) + 1 < NKT) { STAGE_A((p_) ^ 1, (t_) + 1, 1);                       \
                          STAGE_A((p_) ^ 1, (t_) + 1, 3); }                     \
    PHASE_TAIL(0, 0);                                                           \
    /* phase 1 */                                                               \
    LDB(Bb_, 1);                                                                \
    if ((t_) + 2 < NKT) { STAGE_A(p_, (t_) + 2, 0); STAGE_A(p_, (t_) + 2, 2); } \
    PHASE_TAIL(0, 1);                                                           \
    /* phase 2 */                                                               \
    LDA(Ab_, 1);                                                                \
    if ((t_) + 2 < NKT) { STAGE_B(p_, (t_) + 2, 0); STAGE_B(p_, (t_) + 2, 1); } \
    PHASE_TAIL(1, 0);                                                           \
    /* phase 3 */                                                               \
    if ((t_) + 2 < NKT) { STAGE_B(p_, (t_) + 2, 2); STAGE_B(p_, (t_) + 2, 3);   \
        asm volatile("s_waitcnt vmcnt(6)" ::: "memory");                        \
    } else if ((t_) + 1 < NKT) {                                                \
        asm volatile("s_waitcnt vmcnt(0)" ::: "memory");                        \
    }                                                                           \
    PHASE_TAIL(1, 1);                                                           \
} while (0)

    // Prologue: tile0 fully + tile1 {Aq0,Aq2,Bq0..3} (its Aq1,Aq3 land at iter0 ph0)
    #pragma unroll
    for (int q = 0; q < 4; ++q) { STAGE_A(0, 0, q); STAGE_B(0, 0, q); }
    STAGE_A(1, 1, 0); STAGE_A(1, 1, 2);
    #pragma unroll
    for (int q = 0; q < 4; ++q) STAGE_B(1, 1, q);
    asm volatile("s_waitcnt vmcnt(6)" ::: "memory");   // tile0 complete
    __builtin_amdgcn_s_barrier();

    #pragma unroll 1
    for (int kt2 = 0; kt2 < NKT / 2; ++kt2) {
        const int t0 = 2 * kt2;
        TILE_ITER(0, t0);
        TILE_ITER(1, t0 + 1);
    }
#undef TILE_ITER
#undef PHASE_TAIL
#undef MFMA_Q
#undef LDB
#undef LDA
#undef STAGE_B
#undef STAGE_A

    // ---- Fused epilogue (per-m to bound VGPR): logits -> exp2 sums + label.
    //      C/D: class c = bn*256 + wn*64 + n*16 + lo ; row = wm*128 + m*16 + hi*4 + j
    float* red = reinterpret_cast<float*>(&Alds[0][0]);   // [256 rows][4 wn][2]
    #pragma unroll
    for (int m = 0; m < 8; ++m) {
        const int rloc = wm * 128 + m * 16 + hi * 4;
        float rs4[4], s4[4], lb2[4];
        int   lb4[4];
        #pragma unroll
        for (int j = 0; j < 4; ++j) {
            const size_t grow = arow0 + rloc + j;
            rs4[j] = rowscale[grow];   // log2(e)/||h||  (tau = 1)
            lb4[j] = labels[grow];
            s4[j]  = 0.f;
            lb2[j] = -1e30f;
        }
        #pragma unroll
        for (int n = 0; n < 4; ++n) {
            const int c = (int)brow0 + wn * 64 + n * 16 + lo;
            const float pen = (c < CCLS) ? 0.f : -1e30f;
            #pragma unroll
            for (int j = 0; j < 4; ++j) {
                const float lg = fmaf(acc[m][n][j], rs4[j], pen);
                lb2[j] = (c == lb4[j]) ? lg : lb2[j];
                s4[j] += exp2f(lg);
            }
        }
        #pragma unroll
        for (int j = 0; j < 4; ++j) {
            #pragma unroll
            for (int mask = 1; mask <= 8; mask <<= 1) {
                s4[j]  += __shfl_xor(s4[j], mask);
                lb2[j]  = fmaxf(lb2[j], __shfl_xor(lb2[j], mask));
            }
            if (lo == 0) {
                const int r = rloc + j;
                red[(r * 4 + wn) * 2 + 0] = s4[j];
                red[(r * 4 + wn) * 2 + 1] = lb2[j];
            }
        }
    }
    __syncthreads();
    if (tid < 256) {
        float st = 0.f, lt = -1e30f;
        #pragma unroll
        for (int q = 0; q < 4; ++q) {
            st += red[(tid * 4 + q) * 2 + 0];
            lt  = fmaxf(lt, red[(tid * 4 + q) * 2 + 1]);
        }
        const size_t grow = arow0 + tid;
        psum[grow * GN + bn] = st;
        plab[grow * GN + bn] = lt;
    }
}

// ---------------------------------------------------------------------------
// Kernel 3: per-row loss, 64 blocks x 256 rows -> 64 partials (grid-parallel)
// ---------------------------------------------------------------------------
__global__ __launch_bounds__(256) void reduce1(
        const float* __restrict__ psum, const float* __restrict__ plab,
        float* __restrict__ partials) {
    const int tid = threadIdx.x;
    const size_t row = (size_t)blockIdx.x * 256 + tid;
    const float4 ps = *reinterpret_cast<const float4*>(psum + row * GN);
    const float4 pl = *reinterpret_cast<const float4*>(plab + row * GN);
    const float st = (ps.x + ps.y) + (ps.z + ps.w);
    const float lt = fmaxf(fmaxf(pl.x, pl.y), fmaxf(pl.z, pl.w));
    float loss = 0.6931471805599453f * (log2f(st) - lt);
    #pragma unroll
    for (int mask = 1; mask < 64; mask <<= 1)
        loss += __shfl_xor(loss, mask);
    __shared__ float wsum[4];
    if ((tid & 63) == 0) wsum[tid >> 6] = loss;
    __syncthreads();
    if (tid == 0)
        partials[blockIdx.x] = wsum[0] + wsum[1] + wsum[2] + wsum[3];
}

// Kernel 4: final 64 -> 1 mean
__global__ void reduce2(const float* __restrict__ partials, float* __restrict__ out) {
    float v = partials[threadIdx.x];   // 64 threads
    #pragma unroll
    for (int mask = 1; mask < 64; mask <<= 1)
        v += __shfl_xor(v, mask);
    if (threadIdx.x == 0) out[0] = v * (1.0f / 16384.0f);
}

extern "C" void kernel_launch(void* const* d_in, const int* in_sizes, int n_in,
                              void* d_out, int out_size, void* d_ws, size_t ws_size,
                              hipStream_t stream) {
    const float* H      = (const float*)d_in[0];   // [16384, 1024] fp32
    const float* P      = (const float*)d_in[1];   // [1000, 1024] fp32
    const int*   labels = (const int*)d_in[2];     // [16384] int32
    float* out = (float*)d_out;

    // ws layout (~34.6 MiB): Hb 32M | Pb 2M | rowscale 64K | psum 256K | plab 256K
    char* wp = (char*)d_ws;
    unsigned short* Hb = (unsigned short*)wp;   wp += (size_t)B_ROWS * DDIM * 2;
    unsigned short* Pb = (unsigned short*)wp;   wp += (size_t)CPAD * DDIM * 2;
    float* rowscale    = (float*)wp;            wp += (size_t)B_ROWS * 4;
    float* psum        = (float*)wp;            wp += (size_t)B_ROWS * GN * 4;
    float* plab        = (float*)wp;            wp += (size_t)B_ROWS * GN * 4;
    float* partials    = (float*)wp;

    prep<<<2080, 256, 0, stream>>>(H, P, Hb, Pb, rowscale);
    gemm_ce<<<(B_ROWS / 256) * GN, 512, 0, stream>>>(Hb, Pb, labels, rowscale, psum, plab);
    reduce1<<<B_ROWS / 256, 256, 0, stream>>>(psum, plab, partials);
    reduce2<<<1, 64, 0, stream>>>(partials, out);
}